// Round 4
// baseline (1971.505 us; speedup 1.0000x reference)
//
#include <hip/hip_runtime.h>

#define N_NODES 100000
#define N_EDGES 500000
#define NODE_IN 16
#define HID 128
#define INP 132           // padded LDS row stride (floats): keeps 16B alignment, breaks pow-2
#define SCAN_CHUNK 1024
#define NB_SCAN ((N_NODES + SCAN_CHUNK - 1) / SCAN_CHUNK)   // 98

__device__ __forceinline__ float elu_f(float v) {
    return v > 0.f ? v : __expf(v) - 1.f;
}

// ===========================================================================
// CSR-by-dst build: deg -> rowPtr (3-phase scan) -> cursor -> payload reorder
// ===========================================================================
__global__ void deg_count_kernel(const int* __restrict__ ei, int* __restrict__ deg) {
    int e = blockIdx.x * 256 + threadIdx.x;
    if (e < N_EDGES) atomicAdd(&deg[ei[N_EDGES + e]], 1);
}

__global__ __launch_bounds__(1024) void scanA_kernel(const int* __restrict__ deg, int* __restrict__ bsum) {
    __shared__ int s[SCAN_CHUNK];
    int i = blockIdx.x * SCAN_CHUNK + threadIdx.x;
    s[threadIdx.x] = (i < N_NODES) ? deg[i] : 0;
    __syncthreads();
    for (int off = SCAN_CHUNK / 2; off > 0; off >>= 1) {
        if (threadIdx.x < off) s[threadIdx.x] += s[threadIdx.x + off];
        __syncthreads();
    }
    if (threadIdx.x == 0) bsum[blockIdx.x] = s[0];
}

__global__ void scanB_kernel(const int* __restrict__ bsum, int* __restrict__ boff,
                             int* __restrict__ rowPtr) {
    if (threadIdx.x == 0 && blockIdx.x == 0) {
        int r = 0;
        for (int i = 0; i < NB_SCAN; i++) { boff[i] = r; r += bsum[i]; }
        rowPtr[N_NODES] = N_EDGES;     // sentinel for block edge-range lookup
    }
}

__global__ __launch_bounds__(1024) void scanC_kernel(const int* __restrict__ deg,
                                                     const int* __restrict__ boff,
                                                     int* __restrict__ rowPtr,
                                                     int* __restrict__ cursor) {
    __shared__ int bufA[SCAN_CHUNK], bufB[SCAN_CHUNK];
    int i = blockIdx.x * SCAN_CHUNK + threadIdx.x;
    int t = threadIdx.x;
    bufA[t] = (i < N_NODES) ? deg[i] : 0;
    __syncthreads();
    int* src = bufA; int* dst = bufB;
    for (int off = 1; off < SCAN_CHUNK; off <<= 1) {
        dst[t] = (t >= off) ? (src[t - off] + src[t]) : src[t];
        __syncthreads();
        int* tmp = src; src = dst; dst = tmp;
    }
    if (i < N_NODES) {
        int excl = (t == 0) ? 0 : src[t - 1];
        int v = excl + boff[blockIdx.x];
        rowPtr[i] = v;
        cursor[i] = v;
    }
}

// payload reorder: srcA/eaA/dstA in CSR(dst) order — removes one indirection
__global__ void fill_kernel(const int* __restrict__ ei, const float* __restrict__ ea,
                            int* __restrict__ cursor, int* __restrict__ srcA,
                            float* __restrict__ eaA, int* __restrict__ dstA) {
    int e = blockIdx.x * 256 + threadIdx.x;
    if (e < N_EDGES) {
        int d = ei[N_EDGES + e];
        int p = atomicAdd(&cursor[d], 1);
        srcA[p] = ei[e];
        eaA[p] = ea[e];
        dstA[p] = d;
    }
}

// ===========================================================================
// Layer 0 scatter (NODE_IN=16, cheap: 8M atomics)
// ===========================================================================
__global__ __launch_bounds__(256) void scatter0_kernel(
    const float* __restrict__ x, const int* __restrict__ ei,
    const float* __restrict__ ea, const float* __restrict__ We0,
    const float* __restrict__ be0, float* __restrict__ aggr)
{
    int idx = blockIdx.x * 256 + threadIdx.x;
    int e = idx >> 4, c = idx & 15;
    int s = ei[e], d = ei[N_EDGES + e];
    float m = x[s * NODE_IN + c] + ea[e] * We0[c] + be0[c];
    m = fmaxf(m, 0.f);
    atomicAdd(&aggr[d * NODE_IN + c], m);
}

// ---------------------------------------------------------------------------
// 4x4 register-blocked FMA helper: acc[i][c] += r[i][k] * w[k][c]
// ---------------------------------------------------------------------------
__device__ __forceinline__ void fma4x4(float (&acc)[4][4],
    const float4& r0, const float4& r1, const float4& r2, const float4& r3,
    const float4& w0, const float4& w1, const float4& w2, const float4& w3)
{
    float r[4][4] = {{r0.x, r0.y, r0.z, r0.w}, {r1.x, r1.y, r1.z, r1.w},
                     {r2.x, r2.y, r2.z, r2.w}, {r3.x, r3.y, r3.z, r3.w}};
    float w[4][4] = {{w0.x, w0.y, w0.z, w0.w}, {w1.x, w1.y, w1.z, w1.w},
                     {w2.x, w2.y, w2.z, w2.w}, {w3.x, w3.y, w3.z, w3.w}};
#pragma unroll
    for (int i = 0; i < 4; i++)
#pragma unroll
        for (int k = 0; k < 4; k++)
#pragma unroll
            for (int c = 0; c < 4; c++)
                acc[i][c] = fmaf(r[i][k], w[k][c], acc[i][c]);
}

// ===========================================================================
// Layer 0 MLP: h = elu( elu((x+aggr0) @ W1[16,128] + b1) @ W2[128,128] + b2 )
// ===========================================================================
__global__ __launch_bounds__(256) void mlp0_kernel(
    const float* __restrict__ x, const float* __restrict__ aggr,
    const float* __restrict__ W1, const float* __restrict__ b1,
    const float* __restrict__ W2, const float* __restrict__ b2,
    float* __restrict__ h)
{
    __shared__ float in0[32][20];
    __shared__ float mid[32][INP];
    const int t = threadIdx.x;
    const int q = t & 31, g = t >> 5;
    const int c0 = q * 4;
    const int base = blockIdx.x * 32;

    for (int i = t; i < 32 * NODE_IN; i += 256) {
        int r = i >> 4, cc = i & 15;
        int n = base + r;
        in0[r][cc] = x[n * NODE_IN + cc] + aggr[n * NODE_IN + cc];
    }
    __syncthreads();

    float4 bb = *(const float4*)&b1[c0];
    float acc[4][4];
#pragma unroll
    for (int i = 0; i < 4; i++) { acc[i][0] = bb.x; acc[i][1] = bb.y; acc[i][2] = bb.z; acc[i][3] = bb.w; }
    for (int k = 0; k < NODE_IN; k += 4) {
        float4 r0 = *(const float4*)&in0[g * 4 + 0][k];
        float4 r1 = *(const float4*)&in0[g * 4 + 1][k];
        float4 r2 = *(const float4*)&in0[g * 4 + 2][k];
        float4 r3 = *(const float4*)&in0[g * 4 + 3][k];
        float4 w0 = *(const float4*)&W1[(k + 0) * HID + c0];
        float4 w1 = *(const float4*)&W1[(k + 1) * HID + c0];
        float4 w2 = *(const float4*)&W1[(k + 2) * HID + c0];
        float4 w3 = *(const float4*)&W1[(k + 3) * HID + c0];
        fma4x4(acc, r0, r1, r2, r3, w0, w1, w2, w3);
    }
#pragma unroll
    for (int i = 0; i < 4; i++)
        *(float4*)&mid[g * 4 + i][c0] = make_float4(elu_f(acc[i][0]), elu_f(acc[i][1]),
                                                    elu_f(acc[i][2]), elu_f(acc[i][3]));
    __syncthreads();

    float4 bb2 = *(const float4*)&b2[c0];
    float acc2[4][4];
#pragma unroll
    for (int i = 0; i < 4; i++) { acc2[i][0] = bb2.x; acc2[i][1] = bb2.y; acc2[i][2] = bb2.z; acc2[i][3] = bb2.w; }
    for (int k = 0; k < HID; k += 4) {
        float4 r0 = *(const float4*)&mid[g * 4 + 0][k];
        float4 r1 = *(const float4*)&mid[g * 4 + 1][k];
        float4 r2 = *(const float4*)&mid[g * 4 + 2][k];
        float4 r3 = *(const float4*)&mid[g * 4 + 3][k];
        float4 w0 = *(const float4*)&W2[(k + 0) * HID + c0];
        float4 w1 = *(const float4*)&W2[(k + 1) * HID + c0];
        float4 w2 = *(const float4*)&W2[(k + 2) * HID + c0];
        float4 w3 = *(const float4*)&W2[(k + 3) * HID + c0];
        fma4x4(acc2, r0, r1, r2, r3, w0, w1, w2, w3);
    }
#pragma unroll
    for (int i = 0; i < 4; i++)
        *(float4*)&h[(base + g * 4 + i) * HID + c0] = make_float4(
            elu_f(acc2[i][0]), elu_f(acc2[i][1]), elu_f(acc2[i][2]), elu_f(acc2[i][3]));
}

// ===========================================================================
// Fused GINE HID layer, v2: EDGE-PARALLEL gather (CSR contiguous per block,
// LDS atomic accumulate) + Linear-ELU-Linear + outer ELU
// ===========================================================================
__global__ __launch_bounds__(256) void gine_fused_kernel(
    const float* __restrict__ hin, const int* __restrict__ rowPtr,
    const int* __restrict__ srcA, const float* __restrict__ eaA,
    const int* __restrict__ dstA,
    const float* __restrict__ We, const float* __restrict__ be,
    const float* __restrict__ W1, const float* __restrict__ b1,
    const float* __restrict__ W2, const float* __restrict__ b2,
    float* __restrict__ hout)
{
    __shared__ float in[32][INP];
    __shared__ float mid[32][INP];
    const int t = threadIdx.x;
    const int q = t & 31, g = t >> 5;
    const int c0 = q * 4;
    const int base = blockIdx.x * 32;

    // init LDS tile with self term
    for (int i = t; i < 32 * 32; i += 256) {
        int r = i >> 5, cc = (i & 31) * 4;
        *(float4*)&in[r][cc] = *(const float4*)&hin[(base + r) * HID + cc];
    }
    __syncthreads();

    // edge-parallel aggregate: 8 edge-slots x 32 lanes (4 cols each)
    // block's edges are contiguous [rowPtr[base], rowPtr[base+32]) in CSR order
    float4 wev = *(const float4*)&We[c0];
    float4 bev = *(const float4*)&be[c0];
    const int s_start = rowPtr[base];
    const int s_end = rowPtr[base + 32];
    for (int j = s_start + g; j < s_end; j += 8) {
        int s = srcA[j];
        float av = eaA[j];
        int r = dstA[j] - base;
        float4 hv = *(const float4*)&hin[s * HID + c0];
        float m0 = fmaxf(fmaf(av, wev.x, bev.x) + hv.x, 0.f);
        float m1 = fmaxf(fmaf(av, wev.y, bev.y) + hv.y, 0.f);
        float m2 = fmaxf(fmaf(av, wev.z, bev.z) + hv.z, 0.f);
        float m3 = fmaxf(fmaf(av, wev.w, bev.w) + hv.w, 0.f);
        atomicAdd(&in[r][c0 + 0], m0);
        atomicAdd(&in[r][c0 + 1], m1);
        atomicAdd(&in[r][c0 + 2], m2);
        atomicAdd(&in[r][c0 + 3], m3);
    }
    __syncthreads();

    // stage 2: mid = elu(in @ W1 + b1)
    float4 bb = *(const float4*)&b1[c0];
    float acc[4][4];
#pragma unroll
    for (int i = 0; i < 4; i++) { acc[i][0] = bb.x; acc[i][1] = bb.y; acc[i][2] = bb.z; acc[i][3] = bb.w; }
    for (int k = 0; k < HID; k += 4) {
        float4 r0 = *(const float4*)&in[g * 4 + 0][k];
        float4 r1 = *(const float4*)&in[g * 4 + 1][k];
        float4 r2 = *(const float4*)&in[g * 4 + 2][k];
        float4 r3 = *(const float4*)&in[g * 4 + 3][k];
        float4 w0 = *(const float4*)&W1[(k + 0) * HID + c0];
        float4 w1 = *(const float4*)&W1[(k + 1) * HID + c0];
        float4 w2 = *(const float4*)&W1[(k + 2) * HID + c0];
        float4 w3 = *(const float4*)&W1[(k + 3) * HID + c0];
        fma4x4(acc, r0, r1, r2, r3, w0, w1, w2, w3);
    }
#pragma unroll
    for (int i = 0; i < 4; i++)
        *(float4*)&mid[g * 4 + i][c0] = make_float4(elu_f(acc[i][0]), elu_f(acc[i][1]),
                                                    elu_f(acc[i][2]), elu_f(acc[i][3]));
    __syncthreads();

    // stage 3: hout = elu(mid @ W2 + b2)
    float4 bb2 = *(const float4*)&b2[c0];
    float acc2[4][4];
#pragma unroll
    for (int i = 0; i < 4; i++) { acc2[i][0] = bb2.x; acc2[i][1] = bb2.y; acc2[i][2] = bb2.z; acc2[i][3] = bb2.w; }
    for (int k = 0; k < HID; k += 4) {
        float4 r0 = *(const float4*)&mid[g * 4 + 0][k];
        float4 r1 = *(const float4*)&mid[g * 4 + 1][k];
        float4 r2 = *(const float4*)&mid[g * 4 + 2][k];
        float4 r3 = *(const float4*)&mid[g * 4 + 3][k];
        float4 w0 = *(const float4*)&W2[(k + 0) * HID + c0];
        float4 w1 = *(const float4*)&W2[(k + 1) * HID + c0];
        float4 w2 = *(const float4*)&W2[(k + 2) * HID + c0];
        float4 w3 = *(const float4*)&W2[(k + 3) * HID + c0];
        fma4x4(acc2, r0, r1, r2, r3, w0, w1, w2, w3);
    }
#pragma unroll
    for (int i = 0; i < 4; i++)
        *(float4*)&hout[(base + g * 4 + i) * HID + c0] = make_float4(
            elu_f(acc2[i][0]), elu_f(acc2[i][1]), elu_f(acc2[i][2]), elu_f(acc2[i][3]));
}

// ===========================================================================
// Edge predictor, factored:
//   P1 = h @ Wp1[0:128,:],  P2 = h @ Wp1[128:256,:]   (node-level, 6.6 GF)
//   out[e] = elu(P1[src]+P2[dst]+bp1) . Wp2 + bp2     (edge-level, cheap)
// ===========================================================================
__global__ __launch_bounds__(256) void pred_gemm_kernel(
    const float* __restrict__ h, const float* __restrict__ Wp1,
    float* __restrict__ P1, float* __restrict__ P2)
{
    __shared__ float in[32][INP];
    const int t = threadIdx.x;
    const int q = t & 31, g = t >> 5;
    const int c0 = q * 4;
    const int base = blockIdx.x * 32;

    for (int i = t; i < 32 * (HID / 4); i += 256) {
        int r = i >> 5, cc = (i & 31) * 4;
        *(float4*)&in[r][cc] = *(const float4*)&h[(base + r) * HID + cc];
    }
    __syncthreads();

    float acc1[4][4] = {}, acc2[4][4] = {};
    for (int k = 0; k < HID; k += 4) {
        float4 r0 = *(const float4*)&in[g * 4 + 0][k];
        float4 r1 = *(const float4*)&in[g * 4 + 1][k];
        float4 r2 = *(const float4*)&in[g * 4 + 2][k];
        float4 r3 = *(const float4*)&in[g * 4 + 3][k];
        float4 a0 = *(const float4*)&Wp1[(k + 0) * HID + c0];
        float4 a1 = *(const float4*)&Wp1[(k + 1) * HID + c0];
        float4 a2 = *(const float4*)&Wp1[(k + 2) * HID + c0];
        float4 a3 = *(const float4*)&Wp1[(k + 3) * HID + c0];
        fma4x4(acc1, r0, r1, r2, r3, a0, a1, a2, a3);
        float4 b0 = *(const float4*)&Wp1[(HID + k + 0) * HID + c0];
        float4 b1v = *(const float4*)&Wp1[(HID + k + 1) * HID + c0];
        float4 b2v = *(const float4*)&Wp1[(HID + k + 2) * HID + c0];
        float4 b3 = *(const float4*)&Wp1[(HID + k + 3) * HID + c0];
        fma4x4(acc2, r0, r1, r2, r3, b0, b1v, b2v, b3);
    }
#pragma unroll
    for (int i = 0; i < 4; i++) {
        int n = base + g * 4 + i;
        *(float4*)&P1[n * HID + c0] = make_float4(acc1[i][0], acc1[i][1], acc1[i][2], acc1[i][3]);
        *(float4*)&P2[n * HID + c0] = make_float4(acc2[i][0], acc2[i][1], acc2[i][2], acc2[i][3]);
    }
}

__global__ __launch_bounds__(256) void pred_edge_kernel(
    const float* __restrict__ P1, const float* __restrict__ P2,
    const int* __restrict__ ei, const float* __restrict__ bp1,
    const float* __restrict__ Wp2, const float* __restrict__ bp2,
    float* __restrict__ out)
{
    const int t = threadIdx.x;
    const int lane = t & 31;
    const int eloc = t >> 5;
    const int e = blockIdx.x * 8 + eloc;
    const int c0 = lane * 4;

    int s = ei[e], d = ei[N_EDGES + e];
    float4 a = *(const float4*)&P1[s * HID + c0];
    float4 b = *(const float4*)&P2[d * HID + c0];
    float4 bb = *(const float4*)&bp1[c0];
    float4 w = *(const float4*)&Wp2[c0];
    float r = elu_f(a.x + b.x + bb.x) * w.x
            + elu_f(a.y + b.y + bb.y) * w.y
            + elu_f(a.z + b.z + bb.z) * w.z
            + elu_f(a.w + b.w + bb.w) * w.w;
#pragma unroll
    for (int off = 16; off > 0; off >>= 1) r += __shfl_down(r, off, 32);
    if (lane == 0) out[e] = r + bp2[0];
}

// ===========================================================================
extern "C" void kernel_launch(void* const* d_in, const int* in_sizes, int n_in,
                              void* d_out, int out_size, void* d_ws, size_t ws_size,
                              hipStream_t stream) {
    const float* x    = (const float*)d_in[0];
    const int*   ei   = (const int*)d_in[1];
    const float* ea   = (const float*)d_in[2];
    const float* We0  = (const float*)d_in[3];
    const float* be0  = (const float*)d_in[4];
    const float* W10  = (const float*)d_in[5];
    const float* b10  = (const float*)d_in[6];
    const float* W20  = (const float*)d_in[7];
    const float* b20  = (const float*)d_in[8];
    const float* We_s = (const float*)d_in[9];
    const float* be_s = (const float*)d_in[10];
    const float* W1_s = (const float*)d_in[11];
    const float* b1_s = (const float*)d_in[12];
    const float* W2_s = (const float*)d_in[13];
    const float* b2_s = (const float*)d_in[14];
    const float* Wp1  = (const float*)d_in[15];
    const float* bp1  = (const float*)d_in[16];
    const float* Wp2  = (const float*)d_in[17];
    const float* bp2  = (const float*)d_in[18];
    float* out = (float*)d_out;

    // workspace layout: hA | hB | R  (R holds {aggr0 + CSR arrays}, later P2)
    float* hA = (float*)d_ws;                          // 12.8M f32
    float* hB = hA + (size_t)N_NODES * HID;            // 12.8M f32
    float* R  = hB + (size_t)N_NODES * HID;            // 12.8M f32 region

    float* aggr0 = R;                                  // N*16 f32
    int* deg     = (int*)(aggr0 + (size_t)N_NODES * NODE_IN);
    int* rowPtr  = deg + N_NODES;                      // N+1 ints
    int* cursor  = rowPtr + N_NODES + 1;
    int* srcA    = cursor + N_NODES;                   // 500k
    int* dstA    = srcA + N_EDGES;                     // 500k
    float* eaA   = (float*)(dstA + N_EDGES);           // 500k
    int* bsum    = (int*)(eaA + N_EDGES);
    int* boff    = bsum + NB_SCAN;

    float* P1 = hB;                                    // free after layer ping-pong
    float* P2 = R;                                     // CSR dead by pred time

    // ----- CSR build -----
    hipMemsetAsync(deg, 0, N_NODES * sizeof(int), stream);
    deg_count_kernel<<<(N_EDGES + 255) / 256, 256, 0, stream>>>(ei, deg);
    scanA_kernel<<<NB_SCAN, SCAN_CHUNK, 0, stream>>>(deg, bsum);
    scanB_kernel<<<1, 64, 0, stream>>>(bsum, boff, rowPtr);
    scanC_kernel<<<NB_SCAN, SCAN_CHUNK, 0, stream>>>(deg, boff, rowPtr, cursor);
    fill_kernel<<<(N_EDGES + 255) / 256, 256, 0, stream>>>(ei, ea, cursor, srcA, eaA, dstA);

    // ----- layer 0 (NODE_IN -> HID) -----
    hipMemsetAsync(aggr0, 0, (size_t)N_NODES * NODE_IN * sizeof(float), stream);
    scatter0_kernel<<<(N_EDGES * NODE_IN) / 256, 256, 0, stream>>>(x, ei, ea, We0, be0, aggr0);
    mlp0_kernel<<<N_NODES / 32, 256, 0, stream>>>(x, aggr0, W10, b10, W20, b20, hA);

    // ----- layers 1..4 (HID -> HID), ping-pong; ends on hA -----
    float* hin = hA; float* hout = hB;
    for (int l = 0; l < 4; l++) {
        gine_fused_kernel<<<N_NODES / 32, 256, 0, stream>>>(
            hin, rowPtr, srcA, eaA, dstA,
            We_s + l * HID, be_s + l * HID,
            W1_s + (size_t)l * HID * HID, b1_s + l * HID,
            W2_s + (size_t)l * HID * HID, b2_s + l * HID, hout);
        float* tmp = hin; hin = hout; hout = tmp;
    }
    // hin == hA here; hB free

    // ----- edge predictor (factored) -----
    pred_gemm_kernel<<<N_NODES / 32, 256, 0, stream>>>(hin, Wp1, P1, P2);
    pred_edge_kernel<<<N_EDGES / 8, 256, 0, stream>>>(P1, P2, ei, bp1, Wp2, bp2, out);
}

// Round 5
// 1014.839 us; speedup vs baseline: 1.9427x; 1.9427x over previous
//
#include <hip/hip_runtime.h>

#define N_NODES 100000
#define N_EDGES 500000
#define NODE_IN 16
#define HID 128
#define INP 132           // padded LDS row stride (floats): keeps 16B alignment, breaks pow-2
#define SCAN_CHUNK 1024
#define NB_SCAN ((N_NODES + SCAN_CHUNK - 1) / SCAN_CHUNK)   // 98

__device__ __forceinline__ float elu_f(float v) {
    return v > 0.f ? v : __expf(v) - 1.f;
}

// ===========================================================================
// CSR-by-dst build: deg -> rowPtr (3-phase scan) -> cursor -> payload reorder
// ===========================================================================
__global__ void deg_count_kernel(const int* __restrict__ ei, int* __restrict__ deg) {
    int e = blockIdx.x * 256 + threadIdx.x;
    if (e < N_EDGES) atomicAdd(&deg[ei[N_EDGES + e]], 1);
}

__global__ __launch_bounds__(1024) void scanA_kernel(const int* __restrict__ deg, int* __restrict__ bsum) {
    __shared__ int s[SCAN_CHUNK];
    int i = blockIdx.x * SCAN_CHUNK + threadIdx.x;
    s[threadIdx.x] = (i < N_NODES) ? deg[i] : 0;
    __syncthreads();
    for (int off = SCAN_CHUNK / 2; off > 0; off >>= 1) {
        if (threadIdx.x < off) s[threadIdx.x] += s[threadIdx.x + off];
        __syncthreads();
    }
    if (threadIdx.x == 0) bsum[blockIdx.x] = s[0];
}

__global__ void scanB_kernel(const int* __restrict__ bsum, int* __restrict__ boff,
                             int* __restrict__ rowPtr) {
    if (threadIdx.x == 0 && blockIdx.x == 0) {
        int r = 0;
        for (int i = 0; i < NB_SCAN; i++) { boff[i] = r; r += bsum[i]; }
        rowPtr[N_NODES] = N_EDGES;     // sentinel
    }
}

__global__ __launch_bounds__(1024) void scanC_kernel(const int* __restrict__ deg,
                                                     const int* __restrict__ boff,
                                                     int* __restrict__ rowPtr,
                                                     int* __restrict__ cursor) {
    __shared__ int bufA[SCAN_CHUNK], bufB[SCAN_CHUNK];
    int i = blockIdx.x * SCAN_CHUNK + threadIdx.x;
    int t = threadIdx.x;
    bufA[t] = (i < N_NODES) ? deg[i] : 0;
    __syncthreads();
    int* src = bufA; int* dst = bufB;
    for (int off = 1; off < SCAN_CHUNK; off <<= 1) {
        dst[t] = (t >= off) ? (src[t - off] + src[t]) : src[t];
        __syncthreads();
        int* tmp = src; src = dst; dst = tmp;
    }
    if (i < N_NODES) {
        int excl = (t == 0) ? 0 : src[t - 1];
        int v = excl + boff[blockIdx.x];
        rowPtr[i] = v;
        cursor[i] = v;
    }
}

// payload reorder: srcA/eaA in CSR(dst) order — removes one indirection level
__global__ void fill_kernel(const int* __restrict__ ei, const float* __restrict__ ea,
                            int* __restrict__ cursor, int* __restrict__ srcA,
                            float* __restrict__ eaA) {
    int e = blockIdx.x * 256 + threadIdx.x;
    if (e < N_EDGES) {
        int d = ei[N_EDGES + e];
        int p = atomicAdd(&cursor[d], 1);
        srcA[p] = ei[e];
        eaA[p] = ea[e];
    }
}

// ===========================================================================
// Layer 0 scatter (NODE_IN=16, cheap: 8M atomics)
// ===========================================================================
__global__ __launch_bounds__(256) void scatter0_kernel(
    const float* __restrict__ x, const int* __restrict__ ei,
    const float* __restrict__ ea, const float* __restrict__ We0,
    const float* __restrict__ be0, float* __restrict__ aggr)
{
    int idx = blockIdx.x * 256 + threadIdx.x;
    int e = idx >> 4, c = idx & 15;
    int s = ei[e], d = ei[N_EDGES + e];
    float m = x[s * NODE_IN + c] + ea[e] * We0[c] + be0[c];
    m = fmaxf(m, 0.f);
    atomicAdd(&aggr[d * NODE_IN + c], m);
}

// ---------------------------------------------------------------------------
// 4x4 register-blocked FMA helper: acc[i][c] += r[i][k] * w[k][c]
// ---------------------------------------------------------------------------
__device__ __forceinline__ void fma4x4(float (&acc)[4][4],
    const float4& r0, const float4& r1, const float4& r2, const float4& r3,
    const float4& w0, const float4& w1, const float4& w2, const float4& w3)
{
    float r[4][4] = {{r0.x, r0.y, r0.z, r0.w}, {r1.x, r1.y, r1.z, r1.w},
                     {r2.x, r2.y, r2.z, r2.w}, {r3.x, r3.y, r3.z, r3.w}};
    float w[4][4] = {{w0.x, w0.y, w0.z, w0.w}, {w1.x, w1.y, w1.z, w1.w},
                     {w2.x, w2.y, w2.z, w2.w}, {w3.x, w3.y, w3.z, w3.w}};
#pragma unroll
    for (int i = 0; i < 4; i++)
#pragma unroll
        for (int k = 0; k < 4; k++)
#pragma unroll
            for (int c = 0; c < 4; c++)
                acc[i][c] = fmaf(r[i][k], w[k][c], acc[i][c]);
}

// ===========================================================================
// Layer 0 MLP: h = elu( elu((x+aggr0) @ W1[16,128] + b1) @ W2[128,128] + b2 )
// ===========================================================================
__global__ __launch_bounds__(256) void mlp0_kernel(
    const float* __restrict__ x, const float* __restrict__ aggr,
    const float* __restrict__ W1, const float* __restrict__ b1,
    const float* __restrict__ W2, const float* __restrict__ b2,
    float* __restrict__ h)
{
    __shared__ float in0[32][20];
    __shared__ float mid[32][INP];
    const int t = threadIdx.x;
    const int q = t & 31, g = t >> 5;
    const int c0 = q * 4;
    const int base = blockIdx.x * 32;

    for (int i = t; i < 32 * NODE_IN; i += 256) {
        int r = i >> 4, cc = i & 15;
        int n = base + r;
        in0[r][cc] = x[n * NODE_IN + cc] + aggr[n * NODE_IN + cc];
    }
    __syncthreads();

    float4 bb = *(const float4*)&b1[c0];
    float acc[4][4];
#pragma unroll
    for (int i = 0; i < 4; i++) { acc[i][0] = bb.x; acc[i][1] = bb.y; acc[i][2] = bb.z; acc[i][3] = bb.w; }
    for (int k = 0; k < NODE_IN; k += 4) {
        float4 r0 = *(const float4*)&in0[g * 4 + 0][k];
        float4 r1 = *(const float4*)&in0[g * 4 + 1][k];
        float4 r2 = *(const float4*)&in0[g * 4 + 2][k];
        float4 r3 = *(const float4*)&in0[g * 4 + 3][k];
        float4 w0 = *(const float4*)&W1[(k + 0) * HID + c0];
        float4 w1 = *(const float4*)&W1[(k + 1) * HID + c0];
        float4 w2 = *(const float4*)&W1[(k + 2) * HID + c0];
        float4 w3 = *(const float4*)&W1[(k + 3) * HID + c0];
        fma4x4(acc, r0, r1, r2, r3, w0, w1, w2, w3);
    }
#pragma unroll
    for (int i = 0; i < 4; i++)
        *(float4*)&mid[g * 4 + i][c0] = make_float4(elu_f(acc[i][0]), elu_f(acc[i][1]),
                                                    elu_f(acc[i][2]), elu_f(acc[i][3]));
    __syncthreads();

    float4 bb2 = *(const float4*)&b2[c0];
    float acc2[4][4];
#pragma unroll
    for (int i = 0; i < 4; i++) { acc2[i][0] = bb2.x; acc2[i][1] = bb2.y; acc2[i][2] = bb2.z; acc2[i][3] = bb2.w; }
    for (int k = 0; k < HID; k += 4) {
        float4 r0 = *(const float4*)&mid[g * 4 + 0][k];
        float4 r1 = *(const float4*)&mid[g * 4 + 1][k];
        float4 r2 = *(const float4*)&mid[g * 4 + 2][k];
        float4 r3 = *(const float4*)&mid[g * 4 + 3][k];
        float4 w0 = *(const float4*)&W2[(k + 0) * HID + c0];
        float4 w1 = *(const float4*)&W2[(k + 1) * HID + c0];
        float4 w2 = *(const float4*)&W2[(k + 2) * HID + c0];
        float4 w3 = *(const float4*)&W2[(k + 3) * HID + c0];
        fma4x4(acc2, r0, r1, r2, r3, w0, w1, w2, w3);
    }
#pragma unroll
    for (int i = 0; i < 4; i++)
        *(float4*)&h[(base + g * 4 + i) * HID + c0] = make_float4(
            elu_f(acc2[i][0]), elu_f(acc2[i][1]), elu_f(acc2[i][2]), elu_f(acc2[i][3]));
}

// ===========================================================================
// Fused GINE HID layer, v3: NODE-PARALLEL gather with 4-row interleaved
// chase (4x memory-level parallelism, no atomics) + Linear-ELU-Linear + ELU
// ===========================================================================
__global__ __launch_bounds__(256) void gine_fused_kernel(
    const float* __restrict__ hin, const int* __restrict__ rowPtr,
    const int* __restrict__ srcA, const float* __restrict__ eaA,
    const float* __restrict__ We, const float* __restrict__ be,
    const float* __restrict__ W1, const float* __restrict__ b1,
    const float* __restrict__ W2, const float* __restrict__ b2,
    float* __restrict__ hout)
{
    __shared__ float in[32][INP];
    __shared__ float mid[32][INP];
    const int t = threadIdx.x;
    const int q = t & 31, g = t >> 5;
    const int c0 = q * 4;
    const int base = blockIdx.x * 32;

    float4 wev = *(const float4*)&We[c0];
    float4 bev = *(const float4*)&be[c0];

    // --- interleaved 4-row gather: 4 independent chases in flight ---
    int s0[4], e0[4];
    float4 acc[4];
#pragma unroll
    for (int i = 0; i < 4; i++) {
        int n = base + g * 4 + i;
        s0[i] = rowPtr[n];
        e0[i] = rowPtr[n + 1];
        acc[i] = *(const float4*)&hin[n * HID + c0];
    }
    int maxd = 0;
#pragma unroll
    for (int i = 0; i < 4; i++) maxd = max(maxd, e0[i] - s0[i]);

    for (int step = 0; step < maxd; step++) {
        int idx[4]; float av[4]; bool act[4];
#pragma unroll
        for (int i = 0; i < 4; i++) {
            int j = s0[i] + step;
            act[i] = j < e0[i];
            int jc = act[i] ? j : (N_EDGES - 1);   // safe cached dummy
            idx[i] = srcA[jc];
            av[i]  = eaA[jc];
        }
        float4 hv[4];
#pragma unroll
        for (int i = 0; i < 4; i++)
            hv[i] = *(const float4*)&hin[idx[i] * HID + c0];
#pragma unroll
        for (int i = 0; i < 4; i++) {
            if (act[i]) {
                acc[i].x += fmaxf(fmaf(av[i], wev.x, bev.x) + hv[i].x, 0.f);
                acc[i].y += fmaxf(fmaf(av[i], wev.y, bev.y) + hv[i].y, 0.f);
                acc[i].z += fmaxf(fmaf(av[i], wev.z, bev.z) + hv[i].z, 0.f);
                acc[i].w += fmaxf(fmaf(av[i], wev.w, bev.w) + hv[i].w, 0.f);
            }
        }
    }
#pragma unroll
    for (int i = 0; i < 4; i++)
        *(float4*)&in[g * 4 + i][c0] = acc[i];
    __syncthreads();

    // stage 2: mid = elu(in @ W1 + b1)
    float4 bb = *(const float4*)&b1[c0];
    float acc1[4][4];
#pragma unroll
    for (int i = 0; i < 4; i++) { acc1[i][0] = bb.x; acc1[i][1] = bb.y; acc1[i][2] = bb.z; acc1[i][3] = bb.w; }
    for (int k = 0; k < HID; k += 4) {
        float4 r0 = *(const float4*)&in[g * 4 + 0][k];
        float4 r1 = *(const float4*)&in[g * 4 + 1][k];
        float4 r2 = *(const float4*)&in[g * 4 + 2][k];
        float4 r3 = *(const float4*)&in[g * 4 + 3][k];
        float4 w0 = *(const float4*)&W1[(k + 0) * HID + c0];
        float4 w1 = *(const float4*)&W1[(k + 1) * HID + c0];
        float4 w2 = *(const float4*)&W1[(k + 2) * HID + c0];
        float4 w3 = *(const float4*)&W1[(k + 3) * HID + c0];
        fma4x4(acc1, r0, r1, r2, r3, w0, w1, w2, w3);
    }
#pragma unroll
    for (int i = 0; i < 4; i++)
        *(float4*)&mid[g * 4 + i][c0] = make_float4(elu_f(acc1[i][0]), elu_f(acc1[i][1]),
                                                    elu_f(acc1[i][2]), elu_f(acc1[i][3]));
    __syncthreads();

    // stage 3: hout = elu(mid @ W2 + b2)
    float4 bb2 = *(const float4*)&b2[c0];
    float acc2[4][4];
#pragma unroll
    for (int i = 0; i < 4; i++) { acc2[i][0] = bb2.x; acc2[i][1] = bb2.y; acc2[i][2] = bb2.z; acc2[i][3] = bb2.w; }
    for (int k = 0; k < HID; k += 4) {
        float4 r0 = *(const float4*)&mid[g * 4 + 0][k];
        float4 r1 = *(const float4*)&mid[g * 4 + 1][k];
        float4 r2 = *(const float4*)&mid[g * 4 + 2][k];
        float4 r3 = *(const float4*)&mid[g * 4 + 3][k];
        float4 w0 = *(const float4*)&W2[(k + 0) * HID + c0];
        float4 w1 = *(const float4*)&W2[(k + 1) * HID + c0];
        float4 w2 = *(const float4*)&W2[(k + 2) * HID + c0];
        float4 w3 = *(const float4*)&W2[(k + 3) * HID + c0];
        fma4x4(acc2, r0, r1, r2, r3, w0, w1, w2, w3);
    }
#pragma unroll
    for (int i = 0; i < 4; i++)
        *(float4*)&hout[(base + g * 4 + i) * HID + c0] = make_float4(
            elu_f(acc2[i][0]), elu_f(acc2[i][1]), elu_f(acc2[i][2]), elu_f(acc2[i][3]));
}

// ===========================================================================
// Edge predictor, factored:
//   P1 = h @ Wp1[0:128,:],  P2 = h @ Wp1[128:256,:]   (node-level, 6.6 GF)
//   out[e] = elu(P1[src]+P2[dst]+bp1) . Wp2 + bp2     (edge-level, cheap)
// ===========================================================================
__global__ __launch_bounds__(256) void pred_gemm_kernel(
    const float* __restrict__ h, const float* __restrict__ Wp1,
    float* __restrict__ P1, float* __restrict__ P2)
{
    __shared__ float in[32][INP];
    const int t = threadIdx.x;
    const int q = t & 31, g = t >> 5;
    const int c0 = q * 4;
    const int base = blockIdx.x * 32;

    for (int i = t; i < 32 * (HID / 4); i += 256) {
        int r = i >> 5, cc = (i & 31) * 4;
        *(float4*)&in[r][cc] = *(const float4*)&h[(base + r) * HID + cc];
    }
    __syncthreads();

    float acc1[4][4] = {}, acc2[4][4] = {};
    for (int k = 0; k < HID; k += 4) {
        float4 r0 = *(const float4*)&in[g * 4 + 0][k];
        float4 r1 = *(const float4*)&in[g * 4 + 1][k];
        float4 r2 = *(const float4*)&in[g * 4 + 2][k];
        float4 r3 = *(const float4*)&in[g * 4 + 3][k];
        float4 a0 = *(const float4*)&Wp1[(k + 0) * HID + c0];
        float4 a1 = *(const float4*)&Wp1[(k + 1) * HID + c0];
        float4 a2 = *(const float4*)&Wp1[(k + 2) * HID + c0];
        float4 a3 = *(const float4*)&Wp1[(k + 3) * HID + c0];
        fma4x4(acc1, r0, r1, r2, r3, a0, a1, a2, a3);
        float4 b0 = *(const float4*)&Wp1[(HID + k + 0) * HID + c0];
        float4 b1v = *(const float4*)&Wp1[(HID + k + 1) * HID + c0];
        float4 b2v = *(const float4*)&Wp1[(HID + k + 2) * HID + c0];
        float4 b3 = *(const float4*)&Wp1[(HID + k + 3) * HID + c0];
        fma4x4(acc2, r0, r1, r2, r3, b0, b1v, b2v, b3);
    }
#pragma unroll
    for (int i = 0; i < 4; i++) {
        int n = base + g * 4 + i;
        *(float4*)&P1[n * HID + c0] = make_float4(acc1[i][0], acc1[i][1], acc1[i][2], acc1[i][3]);
        *(float4*)&P2[n * HID + c0] = make_float4(acc2[i][0], acc2[i][1], acc2[i][2], acc2[i][3]);
    }
}

__global__ __launch_bounds__(256) void pred_edge_kernel(
    const float* __restrict__ P1, const float* __restrict__ P2,
    const int* __restrict__ ei, const float* __restrict__ bp1,
    const float* __restrict__ Wp2, const float* __restrict__ bp2,
    float* __restrict__ out)
{
    const int t = threadIdx.x;
    const int lane = t & 31;
    const int eloc = t >> 5;
    const int e = blockIdx.x * 8 + eloc;
    const int c0 = lane * 4;

    int s = ei[e], d = ei[N_EDGES + e];
    float4 a = *(const float4*)&P1[s * HID + c0];
    float4 b = *(const float4*)&P2[d * HID + c0];
    float4 bb = *(const float4*)&bp1[c0];
    float4 w = *(const float4*)&Wp2[c0];
    float r = elu_f(a.x + b.x + bb.x) * w.x
            + elu_f(a.y + b.y + bb.y) * w.y
            + elu_f(a.z + b.z + bb.z) * w.z
            + elu_f(a.w + b.w + bb.w) * w.w;
#pragma unroll
    for (int off = 16; off > 0; off >>= 1) r += __shfl_down(r, off, 32);
    if (lane == 0) out[e] = r + bp2[0];
}

// ===========================================================================
extern "C" void kernel_launch(void* const* d_in, const int* in_sizes, int n_in,
                              void* d_out, int out_size, void* d_ws, size_t ws_size,
                              hipStream_t stream) {
    const float* x    = (const float*)d_in[0];
    const int*   ei   = (const int*)d_in[1];
    const float* ea   = (const float*)d_in[2];
    const float* We0  = (const float*)d_in[3];
    const float* be0  = (const float*)d_in[4];
    const float* W10  = (const float*)d_in[5];
    const float* b10  = (const float*)d_in[6];
    const float* W20  = (const float*)d_in[7];
    const float* b20  = (const float*)d_in[8];
    const float* We_s = (const float*)d_in[9];
    const float* be_s = (const float*)d_in[10];
    const float* W1_s = (const float*)d_in[11];
    const float* b1_s = (const float*)d_in[12];
    const float* W2_s = (const float*)d_in[13];
    const float* b2_s = (const float*)d_in[14];
    const float* Wp1  = (const float*)d_in[15];
    const float* bp1  = (const float*)d_in[16];
    const float* Wp2  = (const float*)d_in[17];
    const float* bp2  = (const float*)d_in[18];
    float* out = (float*)d_out;

    // workspace layout: hA | hB | R  (R holds {aggr0 + CSR arrays}, later P2)
    float* hA = (float*)d_ws;                          // 12.8M f32
    float* hB = hA + (size_t)N_NODES * HID;            // 12.8M f32
    float* R  = hB + (size_t)N_NODES * HID;            // 12.8M f32 region

    float* aggr0 = R;                                  // N*16 f32
    int* deg     = (int*)(aggr0 + (size_t)N_NODES * NODE_IN);
    int* rowPtr  = deg + N_NODES;                      // N+1 ints
    int* cursor  = rowPtr + N_NODES + 1;
    int* srcA    = cursor + N_NODES;                   // 500k
    float* eaA   = (float*)(srcA + N_EDGES);           // 500k
    int* bsum    = (int*)(eaA + N_EDGES);
    int* boff    = bsum + NB_SCAN;

    float* P1 = hB;                                    // free after layer ping-pong
    float* P2 = R;                                     // CSR dead by pred time

    // ----- CSR build -----
    hipMemsetAsync(deg, 0, N_NODES * sizeof(int), stream);
    deg_count_kernel<<<(N_EDGES + 255) / 256, 256, 0, stream>>>(ei, deg);
    scanA_kernel<<<NB_SCAN, SCAN_CHUNK, 0, stream>>>(deg, bsum);
    scanB_kernel<<<1, 64, 0, stream>>>(bsum, boff, rowPtr);
    scanC_kernel<<<NB_SCAN, SCAN_CHUNK, 0, stream>>>(deg, boff, rowPtr, cursor);
    fill_kernel<<<(N_EDGES + 255) / 256, 256, 0, stream>>>(ei, ea, cursor, srcA, eaA);

    // ----- layer 0 (NODE_IN -> HID) -----
    hipMemsetAsync(aggr0, 0, (size_t)N_NODES * NODE_IN * sizeof(float), stream);
    scatter0_kernel<<<(N_EDGES * NODE_IN) / 256, 256, 0, stream>>>(x, ei, ea, We0, be0, aggr0);
    mlp0_kernel<<<N_NODES / 32, 256, 0, stream>>>(x, aggr0, W10, b10, W20, b20, hA);

    // ----- layers 1..4 (HID -> HID), ping-pong; ends on hA -----
    float* hin = hA; float* hout = hB;
    for (int l = 0; l < 4; l++) {
        gine_fused_kernel<<<N_NODES / 32, 256, 0, stream>>>(
            hin, rowPtr, srcA, eaA,
            We_s + l * HID, be_s + l * HID,
            W1_s + (size_t)l * HID * HID, b1_s + l * HID,
            W2_s + (size_t)l * HID * HID, b2_s + l * HID, hout);
        float* tmp = hin; hin = hout; hout = tmp;
    }
    // hin == hA here; hB free

    // ----- edge predictor (factored) -----
    pred_gemm_kernel<<<N_NODES / 32, 256, 0, stream>>>(hin, Wp1, P1, P2);
    pred_edge_kernel<<<N_EDGES / 8, 256, 0, stream>>>(P1, P2, ei, bp1, Wp2, bp2, out);
}

// Round 6
// 945.411 us; speedup vs baseline: 2.0853x; 1.0734x over previous
//
#include <hip/hip_runtime.h>

#define N_NODES 100000
#define N_EDGES 500000
#define NODE_IN 16
#define HID 128
#define INP 132           // padded LDS row stride (floats): keeps 16B alignment, breaks pow-2
#define SCAN_CHUNK 1024
#define NB_SCAN ((N_NODES + SCAN_CHUNK - 1) / SCAN_CHUNK)   // 98

__device__ __forceinline__ float elu_f(float v) {
    return v > 0.f ? v : __expf(v) - 1.f;
}

// bf16 pack/unpack (rne), no header dependence
__device__ __forceinline__ unsigned short f2b(float f) {
    unsigned int u = __float_as_uint(f);
    unsigned int r = (u + 0x7fffu + ((u >> 16) & 1u)) >> 16;
    return (unsigned short)r;
}
__device__ __forceinline__ float b2f(unsigned short h) {
    return __uint_as_float((unsigned int)h << 16);
}

// ===========================================================================
// CSR-by-dst build: deg -> rowPtr (3-phase scan) -> cursor -> payload reorder
// ===========================================================================
__global__ void deg_count_kernel(const int* __restrict__ ei, int* __restrict__ deg) {
    int e = blockIdx.x * 256 + threadIdx.x;
    if (e < N_EDGES) atomicAdd(&deg[ei[N_EDGES + e]], 1);
}

__global__ __launch_bounds__(1024) void scanA_kernel(const int* __restrict__ deg, int* __restrict__ bsum) {
    __shared__ int s[SCAN_CHUNK];
    int i = blockIdx.x * SCAN_CHUNK + threadIdx.x;
    s[threadIdx.x] = (i < N_NODES) ? deg[i] : 0;
    __syncthreads();
    for (int off = SCAN_CHUNK / 2; off > 0; off >>= 1) {
        if (threadIdx.x < off) s[threadIdx.x] += s[threadIdx.x + off];
        __syncthreads();
    }
    if (threadIdx.x == 0) bsum[blockIdx.x] = s[0];
}

__global__ void scanB_kernel(const int* __restrict__ bsum, int* __restrict__ boff,
                             int* __restrict__ rowPtr) {
    if (threadIdx.x == 0 && blockIdx.x == 0) {
        int r = 0;
        for (int i = 0; i < NB_SCAN; i++) { boff[i] = r; r += bsum[i]; }
        rowPtr[N_NODES] = N_EDGES;     // sentinel
    }
}

__global__ __launch_bounds__(1024) void scanC_kernel(const int* __restrict__ deg,
                                                     const int* __restrict__ boff,
                                                     int* __restrict__ rowPtr,
                                                     int* __restrict__ cursor) {
    __shared__ int bufA[SCAN_CHUNK], bufB[SCAN_CHUNK];
    int i = blockIdx.x * SCAN_CHUNK + threadIdx.x;
    int t = threadIdx.x;
    bufA[t] = (i < N_NODES) ? deg[i] : 0;
    __syncthreads();
    int* src = bufA; int* dst = bufB;
    for (int off = 1; off < SCAN_CHUNK; off <<= 1) {
        dst[t] = (t >= off) ? (src[t - off] + src[t]) : src[t];
        __syncthreads();
        int* tmp = src; src = dst; dst = tmp;
    }
    if (i < N_NODES) {
        int excl = (t == 0) ? 0 : src[t - 1];
        int v = excl + boff[blockIdx.x];
        rowPtr[i] = v;
        cursor[i] = v;
    }
}

// payload reorder: srcA/eaA in CSR(dst) order — removes one indirection level
__global__ void fill_kernel(const int* __restrict__ ei, const float* __restrict__ ea,
                            int* __restrict__ cursor, int* __restrict__ srcA,
                            float* __restrict__ eaA) {
    int e = blockIdx.x * 256 + threadIdx.x;
    if (e < N_EDGES) {
        int d = ei[N_EDGES + e];
        int p = atomicAdd(&cursor[d], 1);
        srcA[p] = ei[e];
        eaA[p] = ea[e];
    }
}

// ===========================================================================
// Layer 0 scatter (NODE_IN=16, cheap: 8M atomics)
// ===========================================================================
__global__ __launch_bounds__(256) void scatter0_kernel(
    const float* __restrict__ x, const int* __restrict__ ei,
    const float* __restrict__ ea, const float* __restrict__ We0,
    const float* __restrict__ be0, float* __restrict__ aggr)
{
    int idx = blockIdx.x * 256 + threadIdx.x;
    int e = idx >> 4, c = idx & 15;
    int s = ei[e], d = ei[N_EDGES + e];
    float m = x[s * NODE_IN + c] + ea[e] * We0[c] + be0[c];
    m = fmaxf(m, 0.f);
    atomicAdd(&aggr[d * NODE_IN + c], m);
}

// ---------------------------------------------------------------------------
// 4x4 register-blocked FMA helper: acc[i][c] += r[i][k] * w[k][c]
// ---------------------------------------------------------------------------
__device__ __forceinline__ void fma4x4(float (&acc)[4][4],
    const float4& r0, const float4& r1, const float4& r2, const float4& r3,
    const float4& w0, const float4& w1, const float4& w2, const float4& w3)
{
    float r[4][4] = {{r0.x, r0.y, r0.z, r0.w}, {r1.x, r1.y, r1.z, r1.w},
                     {r2.x, r2.y, r2.z, r2.w}, {r3.x, r3.y, r3.z, r3.w}};
    float w[4][4] = {{w0.x, w0.y, w0.z, w0.w}, {w1.x, w1.y, w1.z, w1.w},
                     {w2.x, w2.y, w2.z, w2.w}, {w3.x, w3.y, w3.z, w3.w}};
#pragma unroll
    for (int i = 0; i < 4; i++)
#pragma unroll
        for (int k = 0; k < 4; k++)
#pragma unroll
            for (int c = 0; c < 4; c++)
                acc[i][c] = fmaf(r[i][k], w[k][c], acc[i][c]);
}

// ===========================================================================
// Layer 0 MLP: h = elu( elu((x+aggr0) @ W1[16,128] + b1) @ W2[128,128] + b2 )
// ===========================================================================
__global__ __launch_bounds__(256) void mlp0_kernel(
    const float* __restrict__ x, const float* __restrict__ aggr,
    const float* __restrict__ W1, const float* __restrict__ b1,
    const float* __restrict__ W2, const float* __restrict__ b2,
    float* __restrict__ h)
{
    __shared__ float in0[32][20];
    __shared__ float mid[32][INP];
    const int t = threadIdx.x;
    const int q = t & 31, g = t >> 5;
    const int c0 = q * 4;
    const int base = blockIdx.x * 32;

    for (int i = t; i < 32 * NODE_IN; i += 256) {
        int r = i >> 4, cc = i & 15;
        int n = base + r;
        in0[r][cc] = x[n * NODE_IN + cc] + aggr[n * NODE_IN + cc];
    }
    __syncthreads();

    float4 bb = *(const float4*)&b1[c0];
    float acc[4][4];
#pragma unroll
    for (int i = 0; i < 4; i++) { acc[i][0] = bb.x; acc[i][1] = bb.y; acc[i][2] = bb.z; acc[i][3] = bb.w; }
    for (int k = 0; k < NODE_IN; k += 4) {
        float4 r0 = *(const float4*)&in0[g * 4 + 0][k];
        float4 r1 = *(const float4*)&in0[g * 4 + 1][k];
        float4 r2 = *(const float4*)&in0[g * 4 + 2][k];
        float4 r3 = *(const float4*)&in0[g * 4 + 3][k];
        float4 w0 = *(const float4*)&W1[(k + 0) * HID + c0];
        float4 w1 = *(const float4*)&W1[(k + 1) * HID + c0];
        float4 w2 = *(const float4*)&W1[(k + 2) * HID + c0];
        float4 w3 = *(const float4*)&W1[(k + 3) * HID + c0];
        fma4x4(acc, r0, r1, r2, r3, w0, w1, w2, w3);
    }
#pragma unroll
    for (int i = 0; i < 4; i++)
        *(float4*)&mid[g * 4 + i][c0] = make_float4(elu_f(acc[i][0]), elu_f(acc[i][1]),
                                                    elu_f(acc[i][2]), elu_f(acc[i][3]));
    __syncthreads();

    float4 bb2 = *(const float4*)&b2[c0];
    float acc2[4][4];
#pragma unroll
    for (int i = 0; i < 4; i++) { acc2[i][0] = bb2.x; acc2[i][1] = bb2.y; acc2[i][2] = bb2.z; acc2[i][3] = bb2.w; }
    for (int k = 0; k < HID; k += 4) {
        float4 r0 = *(const float4*)&mid[g * 4 + 0][k];
        float4 r1 = *(const float4*)&mid[g * 4 + 1][k];
        float4 r2 = *(const float4*)&mid[g * 4 + 2][k];
        float4 r3 = *(const float4*)&mid[g * 4 + 3][k];
        float4 w0 = *(const float4*)&W2[(k + 0) * HID + c0];
        float4 w1 = *(const float4*)&W2[(k + 1) * HID + c0];
        float4 w2 = *(const float4*)&W2[(k + 2) * HID + c0];
        float4 w3 = *(const float4*)&W2[(k + 3) * HID + c0];
        fma4x4(acc2, r0, r1, r2, r3, w0, w1, w2, w3);
    }
#pragma unroll
    for (int i = 0; i < 4; i++)
        *(float4*)&h[(base + g * 4 + i) * HID + c0] = make_float4(
            elu_f(acc2[i][0]), elu_f(acc2[i][1]), elu_f(acc2[i][2]), elu_f(acc2[i][3]));
}

// ===========================================================================
// Fused GINE HID layer, v4: node-parallel interleaved gather + MLP, SINGLE
// LDS buffer (rows are wave-local -> in-place overwrite is safe; barriers
// kept at stage boundaries). PRED variant additionally computes
// P1|P2 = h @ Wp1 halves and emits them bf16-packed per node (256 bf16/row).
// ===========================================================================
template <bool PRED>
__global__ __launch_bounds__(256) void gine_fused_kernel(
    const float* __restrict__ hin, const int* __restrict__ rowPtr,
    const int* __restrict__ srcA, const float* __restrict__ eaA,
    const float* __restrict__ We, const float* __restrict__ be,
    const float* __restrict__ W1, const float* __restrict__ b1,
    const float* __restrict__ W2, const float* __restrict__ b2,
    float* __restrict__ hout, const float* __restrict__ Wp1,
    unsigned short* __restrict__ Pbuf)
{
    __shared__ float buf[32][INP];     // 16.9 KB -> 8 blocks/CU
    const int t = threadIdx.x;
    const int q = t & 31, g = t >> 5;
    const int c0 = q * 4;
    const int base = blockIdx.x * 32;

    float4 wev = *(const float4*)&We[c0];
    float4 bev = *(const float4*)&be[c0];

    // --- stage 1: interleaved 4-row gather (4 independent chases in flight) ---
    int s0[4], e0[4];
    float4 acc[4];
#pragma unroll
    for (int i = 0; i < 4; i++) {
        int n = base + g * 4 + i;
        s0[i] = rowPtr[n];
        e0[i] = rowPtr[n + 1];
        acc[i] = *(const float4*)&hin[n * HID + c0];
    }
    int maxd = 0;
#pragma unroll
    for (int i = 0; i < 4; i++) maxd = max(maxd, e0[i] - s0[i]);

    for (int step = 0; step < maxd; step++) {
        int idx[4]; float av[4]; bool act[4];
#pragma unroll
        for (int i = 0; i < 4; i++) {
            int j = s0[i] + step;
            act[i] = j < e0[i];
            int jc = act[i] ? j : (N_EDGES - 1);   // safe cached dummy
            idx[i] = srcA[jc];
            av[i]  = eaA[jc];
        }
        float4 hv[4];
#pragma unroll
        for (int i = 0; i < 4; i++)
            hv[i] = *(const float4*)&hin[idx[i] * HID + c0];
#pragma unroll
        for (int i = 0; i < 4; i++) {
            if (act[i]) {
                acc[i].x += fmaxf(fmaf(av[i], wev.x, bev.x) + hv[i].x, 0.f);
                acc[i].y += fmaxf(fmaf(av[i], wev.y, bev.y) + hv[i].y, 0.f);
                acc[i].z += fmaxf(fmaf(av[i], wev.z, bev.z) + hv[i].z, 0.f);
                acc[i].w += fmaxf(fmaf(av[i], wev.w, bev.w) + hv[i].w, 0.f);
            }
        }
    }
#pragma unroll
    for (int i = 0; i < 4; i++)
        *(float4*)&buf[g * 4 + i][c0] = acc[i];
    __syncthreads();

    // --- stage 2: mid = elu(in @ W1 + b1), written back in place ---
    float4 bb = *(const float4*)&b1[c0];
    float acc1[4][4];
#pragma unroll
    for (int i = 0; i < 4; i++) { acc1[i][0] = bb.x; acc1[i][1] = bb.y; acc1[i][2] = bb.z; acc1[i][3] = bb.w; }
    for (int k = 0; k < HID; k += 4) {
        float4 r0 = *(const float4*)&buf[g * 4 + 0][k];
        float4 r1 = *(const float4*)&buf[g * 4 + 1][k];
        float4 r2 = *(const float4*)&buf[g * 4 + 2][k];
        float4 r3 = *(const float4*)&buf[g * 4 + 3][k];
        float4 w0 = *(const float4*)&W1[(k + 0) * HID + c0];
        float4 w1 = *(const float4*)&W1[(k + 1) * HID + c0];
        float4 w2 = *(const float4*)&W1[(k + 2) * HID + c0];
        float4 w3 = *(const float4*)&W1[(k + 3) * HID + c0];
        fma4x4(acc1, r0, r1, r2, r3, w0, w1, w2, w3);
    }
    // in-place: rows g*4..g*4+3 are only touched by this wave (lockstep-safe)
#pragma unroll
    for (int i = 0; i < 4; i++)
        *(float4*)&buf[g * 4 + i][c0] = make_float4(elu_f(acc1[i][0]), elu_f(acc1[i][1]),
                                                    elu_f(acc1[i][2]), elu_f(acc1[i][3]));
    __syncthreads();

    // --- stage 3: h = elu(mid @ W2 + b2) ---
    float4 bb2 = *(const float4*)&b2[c0];
    float acc2[4][4];
#pragma unroll
    for (int i = 0; i < 4; i++) { acc2[i][0] = bb2.x; acc2[i][1] = bb2.y; acc2[i][2] = bb2.z; acc2[i][3] = bb2.w; }
    for (int k = 0; k < HID; k += 4) {
        float4 r0 = *(const float4*)&buf[g * 4 + 0][k];
        float4 r1 = *(const float4*)&buf[g * 4 + 1][k];
        float4 r2 = *(const float4*)&buf[g * 4 + 2][k];
        float4 r3 = *(const float4*)&buf[g * 4 + 3][k];
        float4 w0 = *(const float4*)&W2[(k + 0) * HID + c0];
        float4 w1 = *(const float4*)&W2[(k + 1) * HID + c0];
        float4 w2 = *(const float4*)&W2[(k + 2) * HID + c0];
        float4 w3 = *(const float4*)&W2[(k + 3) * HID + c0];
        fma4x4(acc2, r0, r1, r2, r3, w0, w1, w2, w3);
    }

    if constexpr (!PRED) {
#pragma unroll
        for (int i = 0; i < 4; i++)
            *(float4*)&hout[(base + g * 4 + i) * HID + c0] = make_float4(
                elu_f(acc2[i][0]), elu_f(acc2[i][1]), elu_f(acc2[i][2]), elu_f(acc2[i][3]));
    } else {
        // h_final only feeds P = h @ Wp1 — keep it in LDS, emit P1|P2 bf16
#pragma unroll
        for (int i = 0; i < 4; i++)
            *(float4*)&buf[g * 4 + i][c0] = make_float4(elu_f(acc2[i][0]), elu_f(acc2[i][1]),
                                                        elu_f(acc2[i][2]), elu_f(acc2[i][3]));
        __syncthreads();

        float accA[4][4] = {}, accB[4][4] = {};
        for (int k = 0; k < HID; k += 4) {
            float4 r0 = *(const float4*)&buf[g * 4 + 0][k];
            float4 r1 = *(const float4*)&buf[g * 4 + 1][k];
            float4 r2 = *(const float4*)&buf[g * 4 + 2][k];
            float4 r3 = *(const float4*)&buf[g * 4 + 3][k];
            float4 a0 = *(const float4*)&Wp1[(k + 0) * HID + c0];
            float4 a1 = *(const float4*)&Wp1[(k + 1) * HID + c0];
            float4 a2 = *(const float4*)&Wp1[(k + 2) * HID + c0];
            float4 a3 = *(const float4*)&Wp1[(k + 3) * HID + c0];
            fma4x4(accA, r0, r1, r2, r3, a0, a1, a2, a3);
            float4 b0 = *(const float4*)&Wp1[(HID + k + 0) * HID + c0];
            float4 b1v = *(const float4*)&Wp1[(HID + k + 1) * HID + c0];
            float4 b2v = *(const float4*)&Wp1[(HID + k + 2) * HID + c0];
            float4 b3 = *(const float4*)&Wp1[(HID + k + 3) * HID + c0];
            fma4x4(accB, r0, r1, r2, r3, b0, b1v, b2v, b3);
        }
#pragma unroll
        for (int i = 0; i < 4; i++) {
            int n = base + g * 4 + i;
            ushort4 pa, pb;
            pa.x = f2b(accA[i][0]); pa.y = f2b(accA[i][1]);
            pa.z = f2b(accA[i][2]); pa.w = f2b(accA[i][3]);
            pb.x = f2b(accB[i][0]); pb.y = f2b(accB[i][1]);
            pb.z = f2b(accB[i][2]); pb.w = f2b(accB[i][3]);
            *(ushort4*)&Pbuf[n * 256 + c0]       = pa;   // P1 half
            *(ushort4*)&Pbuf[n * 256 + 128 + c0] = pb;   // P2 half
        }
    }
}

// ===========================================================================
// Edge predictor tail: out[e] = elu(P1[src]+P2[dst]+bp1) . Wp2 + bp2
// Pbuf: per node 256 bf16 = [P1 row | P2 row]
// ===========================================================================
__global__ __launch_bounds__(256) void pred_edge_kernel(
    const unsigned short* __restrict__ Pbuf, const int* __restrict__ ei,
    const float* __restrict__ bp1, const float* __restrict__ Wp2,
    const float* __restrict__ bp2, float* __restrict__ out)
{
    const int t = threadIdx.x;
    const int lane = t & 31;
    const int eloc = t >> 5;
    const int e = blockIdx.x * 8 + eloc;
    const int c0 = lane * 4;

    int s = ei[e], d = ei[N_EDGES + e];
    ushort4 ua = *(const ushort4*)&Pbuf[s * 256 + c0];
    ushort4 ub = *(const ushort4*)&Pbuf[d * 256 + 128 + c0];
    float4 bb = *(const float4*)&bp1[c0];
    float4 w = *(const float4*)&Wp2[c0];
    float r = elu_f(b2f(ua.x) + b2f(ub.x) + bb.x) * w.x
            + elu_f(b2f(ua.y) + b2f(ub.y) + bb.y) * w.y
            + elu_f(b2f(ua.z) + b2f(ub.z) + bb.z) * w.z
            + elu_f(b2f(ua.w) + b2f(ub.w) + bb.w) * w.w;
#pragma unroll
    for (int off = 16; off > 0; off >>= 1) r += __shfl_down(r, off, 32);
    if (lane == 0) out[e] = r + bp2[0];
}

// ===========================================================================
extern "C" void kernel_launch(void* const* d_in, const int* in_sizes, int n_in,
                              void* d_out, int out_size, void* d_ws, size_t ws_size,
                              hipStream_t stream) {
    const float* x    = (const float*)d_in[0];
    const int*   ei   = (const int*)d_in[1];
    const float* ea   = (const float*)d_in[2];
    const float* We0  = (const float*)d_in[3];
    const float* be0  = (const float*)d_in[4];
    const float* W10  = (const float*)d_in[5];
    const float* b10  = (const float*)d_in[6];
    const float* W20  = (const float*)d_in[7];
    const float* b20  = (const float*)d_in[8];
    const float* We_s = (const float*)d_in[9];
    const float* be_s = (const float*)d_in[10];
    const float* W1_s = (const float*)d_in[11];
    const float* b1_s = (const float*)d_in[12];
    const float* W2_s = (const float*)d_in[13];
    const float* b2_s = (const float*)d_in[14];
    const float* Wp1  = (const float*)d_in[15];
    const float* bp1  = (const float*)d_in[16];
    const float* Wp2  = (const float*)d_in[17];
    const float* bp2  = (const float*)d_in[18];
    float* out = (float*)d_out;

    // workspace layout: hA | hB | R  (R holds {aggr0 + CSR arrays})
    float* hA = (float*)d_ws;                          // 12.8M f32
    float* hB = hA + (size_t)N_NODES * HID;            // 12.8M f32
    float* R  = hB + (size_t)N_NODES * HID;            // 12.8M f32 region

    float* aggr0 = R;                                  // N*16 f32
    int* deg     = (int*)(aggr0 + (size_t)N_NODES * NODE_IN);
    int* rowPtr  = deg + N_NODES;                      // N+1 ints
    int* cursor  = rowPtr + N_NODES + 1;
    int* srcA    = cursor + N_NODES;                   // 500k
    float* eaA   = (float*)(srcA + N_EDGES);           // 500k
    int* bsum    = (int*)(eaA + N_EDGES);
    int* boff    = bsum + NB_SCAN;

    // ----- CSR build -----
    hipMemsetAsync(deg, 0, N_NODES * sizeof(int), stream);
    deg_count_kernel<<<(N_EDGES + 255) / 256, 256, 0, stream>>>(ei, deg);
    scanA_kernel<<<NB_SCAN, SCAN_CHUNK, 0, stream>>>(deg, bsum);
    scanB_kernel<<<1, 64, 0, stream>>>(bsum, boff, rowPtr);
    scanC_kernel<<<NB_SCAN, SCAN_CHUNK, 0, stream>>>(deg, boff, rowPtr, cursor);
    fill_kernel<<<(N_EDGES + 255) / 256, 256, 0, stream>>>(ei, ea, cursor, srcA, eaA);

    // ----- layer 0 (NODE_IN -> HID) -----
    hipMemsetAsync(aggr0, 0, (size_t)N_NODES * NODE_IN * sizeof(float), stream);
    scatter0_kernel<<<(N_EDGES * NODE_IN) / 256, 256, 0, stream>>>(x, ei, ea, We0, be0, aggr0);
    mlp0_kernel<<<N_NODES / 32, 256, 0, stream>>>(x, aggr0, W10, b10, W20, b20, hA);

    // ----- layers 1..3 (HID -> HID), ping-pong: A->B->A->B -----
    float* hin = hA; float* hout = hB;
    for (int l = 0; l < 3; l++) {
        gine_fused_kernel<false><<<N_NODES / 32, 256, 0, stream>>>(
            hin, rowPtr, srcA, eaA,
            We_s + l * HID, be_s + l * HID,
            W1_s + (size_t)l * HID * HID, b1_s + l * HID,
            W2_s + (size_t)l * HID * HID, b2_s + l * HID, hout, nullptr, nullptr);
        float* tmp = hin; hin = hout; hout = tmp;
    }
    // hin == hB; hA free -> holds bf16 P1|P2 (100k * 256 * 2B = 51.2 MB)

    // ----- layer 4 fused with pred GEMM -----
    unsigned short* Pbuf = (unsigned short*)hA;
    {
        const int l = 3;
        gine_fused_kernel<true><<<N_NODES / 32, 256, 0, stream>>>(
            hin, rowPtr, srcA, eaA,
            We_s + l * HID, be_s + l * HID,
            W1_s + (size_t)l * HID * HID, b1_s + l * HID,
            W2_s + (size_t)l * HID * HID, b2_s + l * HID, nullptr, Wp1, Pbuf);
    }

    // ----- edge predictor tail -----
    pred_edge_kernel<<<N_EDGES / 8, 256, 0, stream>>>(Pbuf, ei, bp1, Wp2, bp2, out);
}

// Round 7
// 918.976 us; speedup vs baseline: 2.1453x; 1.0288x over previous
//
#include <hip/hip_runtime.h>

#define N_NODES 100000
#define N_EDGES 500000
#define NODE_IN 16
#define HID 128
#define INP 132           // padded LDS row stride (floats): keeps 16B alignment, breaks pow-2
#define SCAN_CHUNK 1024
#define NB_SCAN ((N_NODES + SCAN_CHUNK - 1) / SCAN_CHUNK)   // 98

__device__ __forceinline__ float elu_f(float v) {
    return v > 0.f ? v : __expf(v) - 1.f;
}

// bf16 pack/unpack (rne)
__device__ __forceinline__ unsigned short f2b(float f) {
    unsigned int u = __float_as_uint(f);
    unsigned int r = (u + 0x7fffu + ((u >> 16) & 1u)) >> 16;
    return (unsigned short)r;
}
__device__ __forceinline__ float b2f(unsigned short h) {
    return __uint_as_float((unsigned int)h << 16);
}

// ===========================================================================
// CSR-by-dst build: deg -> rowPtr (3-phase scan) -> cursor -> payload reorder
// ===========================================================================
__global__ void deg_count_kernel(const int* __restrict__ ei, int* __restrict__ deg) {
    int e = blockIdx.x * 256 + threadIdx.x;
    if (e < N_EDGES) atomicAdd(&deg[ei[N_EDGES + e]], 1);
}

__global__ __launch_bounds__(1024) void scanA_kernel(const int* __restrict__ deg, int* __restrict__ bsum) {
    __shared__ int s[SCAN_CHUNK];
    int i = blockIdx.x * SCAN_CHUNK + threadIdx.x;
    s[threadIdx.x] = (i < N_NODES) ? deg[i] : 0;
    __syncthreads();
    for (int off = SCAN_CHUNK / 2; off > 0; off >>= 1) {
        if (threadIdx.x < off) s[threadIdx.x] += s[threadIdx.x + off];
        __syncthreads();
    }
    if (threadIdx.x == 0) bsum[blockIdx.x] = s[0];
}

__global__ void scanB_kernel(const int* __restrict__ bsum, int* __restrict__ boff,
                             int* __restrict__ rowPtr) {
    if (threadIdx.x == 0 && blockIdx.x == 0) {
        int r = 0;
        for (int i = 0; i < NB_SCAN; i++) { boff[i] = r; r += bsum[i]; }
        rowPtr[N_NODES] = N_EDGES;     // sentinel
    }
}

__global__ __launch_bounds__(1024) void scanC_kernel(const int* __restrict__ deg,
                                                     const int* __restrict__ boff,
                                                     int* __restrict__ rowPtr,
                                                     int* __restrict__ cursor) {
    __shared__ int bufA[SCAN_CHUNK], bufB[SCAN_CHUNK];
    int i = blockIdx.x * SCAN_CHUNK + threadIdx.x;
    int t = threadIdx.x;
    bufA[t] = (i < N_NODES) ? deg[i] : 0;
    __syncthreads();
    int* src = bufA; int* dst = bufB;
    for (int off = 1; off < SCAN_CHUNK; off <<= 1) {
        dst[t] = (t >= off) ? (src[t - off] + src[t]) : src[t];
        __syncthreads();
        int* tmp = src; src = dst; dst = tmp;
    }
    if (i < N_NODES) {
        int excl = (t == 0) ? 0 : src[t - 1];
        int v = excl + boff[blockIdx.x];
        rowPtr[i] = v;
        cursor[i] = v;
    }
}

// payload reorder: srcA/eaA in CSR(dst) order — removes one indirection level
__global__ void fill_kernel(const int* __restrict__ ei, const float* __restrict__ ea,
                            int* __restrict__ cursor, int* __restrict__ srcA,
                            float* __restrict__ eaA) {
    int e = blockIdx.x * 256 + threadIdx.x;
    if (e < N_EDGES) {
        int d = ei[N_EDGES + e];
        int p = atomicAdd(&cursor[d], 1);
        srcA[p] = ei[e];
        eaA[p] = ea[e];
    }
}

// ===========================================================================
// Layer 0 scatter (NODE_IN=16, cheap: 8M atomics)
// ===========================================================================
__global__ __launch_bounds__(256) void scatter0_kernel(
    const float* __restrict__ x, const int* __restrict__ ei,
    const float* __restrict__ ea, const float* __restrict__ We0,
    const float* __restrict__ be0, float* __restrict__ aggr)
{
    int idx = blockIdx.x * 256 + threadIdx.x;
    int e = idx >> 4, c = idx & 15;
    int s = ei[e], d = ei[N_EDGES + e];
    float m = x[s * NODE_IN + c] + ea[e] * We0[c] + be0[c];
    m = fmaxf(m, 0.f);
    atomicAdd(&aggr[d * NODE_IN + c], m);
}

// ---------------------------------------------------------------------------
// 4x4 register-blocked FMA helper: acc[i][c] += r[i][k] * w[k][c]
// ---------------------------------------------------------------------------
__device__ __forceinline__ void fma4x4(float (&acc)[4][4],
    const float4& r0, const float4& r1, const float4& r2, const float4& r3,
    const float4& w0, const float4& w1, const float4& w2, const float4& w3)
{
    float r[4][4] = {{r0.x, r0.y, r0.z, r0.w}, {r1.x, r1.y, r1.z, r1.w},
                     {r2.x, r2.y, r2.z, r2.w}, {r3.x, r3.y, r3.z, r3.w}};
    float w[4][4] = {{w0.x, w0.y, w0.z, w0.w}, {w1.x, w1.y, w1.z, w1.w},
                     {w2.x, w2.y, w2.z, w2.w}, {w3.x, w3.y, w3.z, w3.w}};
#pragma unroll
    for (int i = 0; i < 4; i++)
#pragma unroll
        for (int k = 0; k < 4; k++)
#pragma unroll
            for (int c = 0; c < 4; c++)
                acc[i][c] = fmaf(r[i][k], w[k][c], acc[i][c]);
}

// ===========================================================================
// Layer 0 MLP: h = elu( elu((x+aggr0) @ W1[16,128] + b1) @ W2[128,128] + b2 )
// ===========================================================================
__global__ __launch_bounds__(256) void mlp0_kernel(
    const float* __restrict__ x, const float* __restrict__ aggr,
    const float* __restrict__ W1, const float* __restrict__ b1,
    const float* __restrict__ W2, const float* __restrict__ b2,
    float* __restrict__ h)
{
    __shared__ float in0[32][20];
    __shared__ float mid[32][INP];
    const int t = threadIdx.x;
    const int q = t & 31, g = t >> 5;
    const int c0 = q * 4;
    const int base = blockIdx.x * 32;

    for (int i = t; i < 32 * NODE_IN; i += 256) {
        int r = i >> 4, cc = i & 15;
        int n = base + r;
        in0[r][cc] = x[n * NODE_IN + cc] + aggr[n * NODE_IN + cc];
    }
    __syncthreads();

    float4 bb = *(const float4*)&b1[c0];
    float acc[4][4];
#pragma unroll
    for (int i = 0; i < 4; i++) { acc[i][0] = bb.x; acc[i][1] = bb.y; acc[i][2] = bb.z; acc[i][3] = bb.w; }
    for (int k = 0; k < NODE_IN; k += 4) {
        float4 r0 = *(const float4*)&in0[g * 4 + 0][k];
        float4 r1 = *(const float4*)&in0[g * 4 + 1][k];
        float4 r2 = *(const float4*)&in0[g * 4 + 2][k];
        float4 r3 = *(const float4*)&in0[g * 4 + 3][k];
        float4 w0 = *(const float4*)&W1[(k + 0) * HID + c0];
        float4 w1 = *(const float4*)&W1[(k + 1) * HID + c0];
        float4 w2 = *(const float4*)&W1[(k + 2) * HID + c0];
        float4 w3 = *(const float4*)&W1[(k + 3) * HID + c0];
        fma4x4(acc, r0, r1, r2, r3, w0, w1, w2, w3);
    }
#pragma unroll
    for (int i = 0; i < 4; i++)
        *(float4*)&mid[g * 4 + i][c0] = make_float4(elu_f(acc[i][0]), elu_f(acc[i][1]),
                                                    elu_f(acc[i][2]), elu_f(acc[i][3]));
    __syncthreads();

    float4 bb2 = *(const float4*)&b2[c0];
    float acc2[4][4];
#pragma unroll
    for (int i = 0; i < 4; i++) { acc2[i][0] = bb2.x; acc2[i][1] = bb2.y; acc2[i][2] = bb2.z; acc2[i][3] = bb2.w; }
    for (int k = 0; k < HID; k += 4) {
        float4 r0 = *(const float4*)&mid[g * 4 + 0][k];
        float4 r1 = *(const float4*)&mid[g * 4 + 1][k];
        float4 r2 = *(const float4*)&mid[g * 4 + 2][k];
        float4 r3 = *(const float4*)&mid[g * 4 + 3][k];
        float4 w0 = *(const float4*)&W2[(k + 0) * HID + c0];
        float4 w1 = *(const float4*)&W2[(k + 1) * HID + c0];
        float4 w2 = *(const float4*)&W2[(k + 2) * HID + c0];
        float4 w3 = *(const float4*)&W2[(k + 3) * HID + c0];
        fma4x4(acc2, r0, r1, r2, r3, w0, w1, w2, w3);
    }
#pragma unroll
    for (int i = 0; i < 4; i++)
        *(float4*)&h[(base + g * 4 + i) * HID + c0] = make_float4(
            elu_f(acc2[i][0]), elu_f(acc2[i][1]), elu_f(acc2[i][2]), elu_f(acc2[i][3]));
}

// ===========================================================================
// Fused GINE HID layer, v5: node-parallel gather, step-loop UNROLLED x2
// (8 independent row-gathers in flight), two LDS buffers (round-5 structure).
// PRED variant fuses P1|P2 = h @ Wp1, emits bf16-packed rows.
// ===========================================================================
template <bool PRED>
__global__ __launch_bounds__(256) void gine_fused_kernel(
    const float* __restrict__ hin, const int* __restrict__ rowPtr,
    const int* __restrict__ srcA, const float* __restrict__ eaA,
    const float* __restrict__ We, const float* __restrict__ be,
    const float* __restrict__ W1, const float* __restrict__ b1,
    const float* __restrict__ W2, const float* __restrict__ b2,
    float* __restrict__ hout, const float* __restrict__ Wp1,
    unsigned short* __restrict__ Pbuf)
{
    __shared__ float in[32][INP];
    __shared__ float mid[32][INP];
    const int t = threadIdx.x;
    const int q = t & 31, g = t >> 5;
    const int c0 = q * 4;
    const int base = blockIdx.x * 32;

    float4 wev = *(const float4*)&We[c0];
    float4 bev = *(const float4*)&be[c0];

    // --- stage 1: gather, 4 rows x 2 steps = 8 chases in flight ---
    int s0[4], e0[4];
    float4 acc[4];
#pragma unroll
    for (int i = 0; i < 4; i++) {
        int n = base + g * 4 + i;
        s0[i] = rowPtr[n];
        e0[i] = rowPtr[n + 1];
        acc[i] = *(const float4*)&hin[n * HID + c0];
    }
    int maxd = 0;
#pragma unroll
    for (int i = 0; i < 4; i++) maxd = max(maxd, e0[i] - s0[i]);

    for (int step = 0; step < maxd; step += 2) {
        int idx[8]; float av[8]; bool act[8];
#pragma unroll
        for (int u = 0; u < 2; u++)
#pragma unroll
            for (int i = 0; i < 4; i++) {
                int slot = u * 4 + i;
                int j = s0[i] + step + u;
                act[slot] = j < e0[i];
                int jc = act[slot] ? j : (N_EDGES - 1);   // safe cached dummy
                idx[slot] = srcA[jc];
                av[slot]  = eaA[jc];
            }
        float4 hv[8];
#pragma unroll
        for (int slot = 0; slot < 8; slot++)
            hv[slot] = *(const float4*)&hin[idx[slot] * HID + c0];
#pragma unroll
        for (int u = 0; u < 2; u++)
#pragma unroll
            for (int i = 0; i < 4; i++) {
                int slot = u * 4 + i;
                if (act[slot]) {
                    acc[i].x += fmaxf(fmaf(av[slot], wev.x, bev.x) + hv[slot].x, 0.f);
                    acc[i].y += fmaxf(fmaf(av[slot], wev.y, bev.y) + hv[slot].y, 0.f);
                    acc[i].z += fmaxf(fmaf(av[slot], wev.z, bev.z) + hv[slot].z, 0.f);
                    acc[i].w += fmaxf(fmaf(av[slot], wev.w, bev.w) + hv[slot].w, 0.f);
                }
            }
    }
#pragma unroll
    for (int i = 0; i < 4; i++)
        *(float4*)&in[g * 4 + i][c0] = acc[i];
    __syncthreads();

    // --- stage 2: mid = elu(in @ W1 + b1) ---
    float4 bb = *(const float4*)&b1[c0];
    float acc1[4][4];
#pragma unroll
    for (int i = 0; i < 4; i++) { acc1[i][0] = bb.x; acc1[i][1] = bb.y; acc1[i][2] = bb.z; acc1[i][3] = bb.w; }
    for (int k = 0; k < HID; k += 4) {
        float4 r0 = *(const float4*)&in[g * 4 + 0][k];
        float4 r1 = *(const float4*)&in[g * 4 + 1][k];
        float4 r2 = *(const float4*)&in[g * 4 + 2][k];
        float4 r3 = *(const float4*)&in[g * 4 + 3][k];
        float4 w0 = *(const float4*)&W1[(k + 0) * HID + c0];
        float4 w1 = *(const float4*)&W1[(k + 1) * HID + c0];
        float4 w2 = *(const float4*)&W1[(k + 2) * HID + c0];
        float4 w3 = *(const float4*)&W1[(k + 3) * HID + c0];
        fma4x4(acc1, r0, r1, r2, r3, w0, w1, w2, w3);
    }
#pragma unroll
    for (int i = 0; i < 4; i++)
        *(float4*)&mid[g * 4 + i][c0] = make_float4(elu_f(acc1[i][0]), elu_f(acc1[i][1]),
                                                    elu_f(acc1[i][2]), elu_f(acc1[i][3]));
    __syncthreads();

    // --- stage 3: h = elu(mid @ W2 + b2) ---
    float4 bb2 = *(const float4*)&b2[c0];
    float acc2[4][4];
#pragma unroll
    for (int i = 0; i < 4; i++) { acc2[i][0] = bb2.x; acc2[i][1] = bb2.y; acc2[i][2] = bb2.z; acc2[i][3] = bb2.w; }
    for (int k = 0; k < HID; k += 4) {
        float4 r0 = *(const float4*)&mid[g * 4 + 0][k];
        float4 r1 = *(const float4*)&mid[g * 4 + 1][k];
        float4 r2 = *(const float4*)&mid[g * 4 + 2][k];
        float4 r3 = *(const float4*)&mid[g * 4 + 3][k];
        float4 w0 = *(const float4*)&W2[(k + 0) * HID + c0];
        float4 w1 = *(const float4*)&W2[(k + 1) * HID + c0];
        float4 w2 = *(const float4*)&W2[(k + 2) * HID + c0];
        float4 w3 = *(const float4*)&W2[(k + 3) * HID + c0];
        fma4x4(acc2, r0, r1, r2, r3, w0, w1, w2, w3);
    }

    if constexpr (!PRED) {
#pragma unroll
        for (int i = 0; i < 4; i++)
            *(float4*)&hout[(base + g * 4 + i) * HID + c0] = make_float4(
                elu_f(acc2[i][0]), elu_f(acc2[i][1]), elu_f(acc2[i][2]), elu_f(acc2[i][3]));
    } else {
        // h_final only feeds P = h @ Wp1 — stash h in the (now free) in-buffer
#pragma unroll
        for (int i = 0; i < 4; i++)
            *(float4*)&in[g * 4 + i][c0] = make_float4(elu_f(acc2[i][0]), elu_f(acc2[i][1]),
                                                       elu_f(acc2[i][2]), elu_f(acc2[i][3]));
        __syncthreads();

        float accA[4][4] = {}, accB[4][4] = {};
        for (int k = 0; k < HID; k += 4) {
            float4 r0 = *(const float4*)&in[g * 4 + 0][k];
            float4 r1 = *(const float4*)&in[g * 4 + 1][k];
            float4 r2 = *(const float4*)&in[g * 4 + 2][k];
            float4 r3 = *(const float4*)&in[g * 4 + 3][k];
            float4 a0 = *(const float4*)&Wp1[(k + 0) * HID + c0];
            float4 a1 = *(const float4*)&Wp1[(k + 1) * HID + c0];
            float4 a2 = *(const float4*)&Wp1[(k + 2) * HID + c0];
            float4 a3 = *(const float4*)&Wp1[(k + 3) * HID + c0];
            fma4x4(accA, r0, r1, r2, r3, a0, a1, a2, a3);
            float4 b0 = *(const float4*)&Wp1[(HID + k + 0) * HID + c0];
            float4 b1v = *(const float4*)&Wp1[(HID + k + 1) * HID + c0];
            float4 b2v = *(const float4*)&Wp1[(HID + k + 2) * HID + c0];
            float4 b3 = *(const float4*)&Wp1[(HID + k + 3) * HID + c0];
            fma4x4(accB, r0, r1, r2, r3, b0, b1v, b2v, b3);
        }
#pragma unroll
        for (int i = 0; i < 4; i++) {
            int n = base + g * 4 + i;
            ushort4 pa, pb;
            pa.x = f2b(accA[i][0]); pa.y = f2b(accA[i][1]);
            pa.z = f2b(accA[i][2]); pa.w = f2b(accA[i][3]);
            pb.x = f2b(accB[i][0]); pb.y = f2b(accB[i][1]);
            pb.z = f2b(accB[i][2]); pb.w = f2b(accB[i][3]);
            *(ushort4*)&Pbuf[n * 256 + c0]       = pa;   // P1 half
            *(ushort4*)&Pbuf[n * 256 + 128 + c0] = pb;   // P2 half
        }
    }
}

// ===========================================================================
// Edge predictor tail: out[e] = elu(P1[src]+P2[dst]+bp1) . Wp2 + bp2
// Pbuf: per node 256 bf16 = [P1 row | P2 row]
// ===========================================================================
__global__ __launch_bounds__(256) void pred_edge_kernel(
    const unsigned short* __restrict__ Pbuf, const int* __restrict__ ei,
    const float* __restrict__ bp1, const float* __restrict__ Wp2,
    const float* __restrict__ bp2, float* __restrict__ out)
{
    const int t = threadIdx.x;
    const int lane = t & 31;
    const int eloc = t >> 5;
    const int e = blockIdx.x * 8 + eloc;
    const int c0 = lane * 4;

    int s = ei[e], d = ei[N_EDGES + e];
    ushort4 ua = *(const ushort4*)&Pbuf[s * 256 + c0];
    ushort4 ub = *(const ushort4*)&Pbuf[d * 256 + 128 + c0];
    float4 bb = *(const float4*)&bp1[c0];
    float4 w = *(const float4*)&Wp2[c0];
    float r = elu_f(b2f(ua.x) + b2f(ub.x) + bb.x) * w.x
            + elu_f(b2f(ua.y) + b2f(ub.y) + bb.y) * w.y
            + elu_f(b2f(ua.z) + b2f(ub.z) + bb.z) * w.z
            + elu_f(b2f(ua.w) + b2f(ub.w) + bb.w) * w.w;
#pragma unroll
    for (int off = 16; off > 0; off >>= 1) r += __shfl_down(r, off, 32);
    if (lane == 0) out[e] = r + bp2[0];
}

// ===========================================================================
extern "C" void kernel_launch(void* const* d_in, const int* in_sizes, int n_in,
                              void* d_out, int out_size, void* d_ws, size_t ws_size,
                              hipStream_t stream) {
    const float* x    = (const float*)d_in[0];
    const int*   ei   = (const int*)d_in[1];
    const float* ea   = (const float*)d_in[2];
    const float* We0  = (const float*)d_in[3];
    const float* be0  = (const float*)d_in[4];
    const float* W10  = (const float*)d_in[5];
    const float* b10  = (const float*)d_in[6];
    const float* W20  = (const float*)d_in[7];
    const float* b20  = (const float*)d_in[8];
    const float* We_s = (const float*)d_in[9];
    const float* be_s = (const float*)d_in[10];
    const float* W1_s = (const float*)d_in[11];
    const float* b1_s = (const float*)d_in[12];
    const float* W2_s = (const float*)d_in[13];
    const float* b2_s = (const float*)d_in[14];
    const float* Wp1  = (const float*)d_in[15];
    const float* bp1  = (const float*)d_in[16];
    const float* Wp2  = (const float*)d_in[17];
    const float* bp2  = (const float*)d_in[18];
    float* out = (float*)d_out;

    // workspace layout: hA | hB | R  (R holds {aggr0 + CSR arrays})
    float* hA = (float*)d_ws;                          // 12.8M f32
    float* hB = hA + (size_t)N_NODES * HID;            // 12.8M f32
    float* R  = hB + (size_t)N_NODES * HID;            // 12.8M f32 region

    float* aggr0 = R;                                  // N*16 f32
    int* deg     = (int*)(aggr0 + (size_t)N_NODES * NODE_IN);
    int* rowPtr  = deg + N_NODES;                      // N+1 ints
    int* cursor  = rowPtr + N_NODES + 1;
    int* srcA    = cursor + N_NODES;                   // 500k
    float* eaA   = (float*)(srcA + N_EDGES);           // 500k
    int* bsum    = (int*)(eaA + N_EDGES);
    int* boff    = bsum + NB_SCAN;

    // ----- CSR build -----
    hipMemsetAsync(deg, 0, N_NODES * sizeof(int), stream);
    deg_count_kernel<<<(N_EDGES + 255) / 256, 256, 0, stream>>>(ei, deg);
    scanA_kernel<<<NB_SCAN, SCAN_CHUNK, 0, stream>>>(deg, bsum);
    scanB_kernel<<<1, 64, 0, stream>>>(bsum, boff, rowPtr);
    scanC_kernel<<<NB_SCAN, SCAN_CHUNK, 0, stream>>>(deg, boff, rowPtr, cursor);
    fill_kernel<<<(N_EDGES + 255) / 256, 256, 0, stream>>>(ei, ea, cursor, srcA, eaA);

    // ----- layer 0 (NODE_IN -> HID) -----
    hipMemsetAsync(aggr0, 0, (size_t)N_NODES * NODE_IN * sizeof(float), stream);
    scatter0_kernel<<<(N_EDGES * NODE_IN) / 256, 256, 0, stream>>>(x, ei, ea, We0, be0, aggr0);
    mlp0_kernel<<<N_NODES / 32, 256, 0, stream>>>(x, aggr0, W10, b10, W20, b20, hA);

    // ----- layers 1..3 (HID -> HID), ping-pong: A->B->A->B -----
    float* hin = hA; float* hout = hB;
    for (int l = 0; l < 3; l++) {
        gine_fused_kernel<false><<<N_NODES / 32, 256, 0, stream>>>(
            hin, rowPtr, srcA, eaA,
            We_s + l * HID, be_s + l * HID,
            W1_s + (size_t)l * HID * HID, b1_s + l * HID,
            W2_s + (size_t)l * HID * HID, b2_s + l * HID, hout, nullptr, nullptr);
        float* tmp = hin; hin = hout; hout = tmp;
    }
    // hin == hB; hA free -> holds bf16 P1|P2 (100k * 256 * 2B = 51.2 MB)

    // ----- layer 4 fused with pred GEMM -----
    unsigned short* Pbuf = (unsigned short*)hA;
    {
        const int l = 3;
        gine_fused_kernel<true><<<N_NODES / 32, 256, 0, stream>>>(
            hin, rowPtr, srcA, eaA,
            We_s + l * HID, be_s + l * HID,
            W1_s + (size_t)l * HID * HID, b1_s + l * HID,
            W2_s + (size_t)l * HID * HID, b2_s + l * HID, nullptr, Wp1, Pbuf);
    }

    // ----- edge predictor tail -----
    pred_edge_kernel<<<N_EDGES / 8, 256, 0, stream>>>(Pbuf, ei, bp1, Wp2, bp2, out);
}